// Round 2
// baseline (48.787 us; speedup 1.0000x reference)
//
#include <hip/hip_runtime.h>

typedef unsigned short ushort_t;
typedef unsigned int uint_t;
typedef __bf16 bf16x8 __attribute__((ext_vector_type(8)));
typedef float f32x4 __attribute__((ext_vector_type(4)));

#define H 256
#define RPB 16  // batch rows per block

// output layout (f32): [nb 4096][bdot 4096][y 4096*256][yy 4096*64]
#define NB_OFF 0
#define BDOT_OFF 4096
#define Y_OFF 8192
#define YY_OFF (8192 + 4096 * 256)

__device__ __forceinline__ ushort_t f2bf(float x) {
    union { float f; uint_t u; } c; c.f = x;
    uint_t r = (c.u + 0x7FFFu + ((c.u >> 16) & 1u)) >> 16;  // RNE
    return (ushort_t)r;
}
__device__ __forceinline__ float bf2f(ushort_t v) {
    union { uint_t u; float f; } c; c.u = ((uint_t)v) << 16;
    return c.f;
}

// ws layout (ushort/bf16 units)
#define O_W1b  0        // [256][64]   orig layout (B for z-stage)
#define O_W1T  16384    // [64][256]   W1T[i][g] = w1[g][i]
#define O_W2ab 32768    // [256][256]  orig
#define O_W2bb 98304
#define O_W3ab 163840
#define O_W2aT 229376   // W2aT[g][h] = w2a[h][g]
#define O_W2bT 294912
#define O_W3aT 360448   // W3aT[h][o] = w3a[o][h]
#define O_W3sb 425984   // [256][64] orig
#define O_W3sT 442368   // [64][256] W3sT[i][o] = w3s[o][i]

// Coalesced convert + dual-layout store. One block = one 64x64 tile.
__global__ __launch_bounds__(256) void prep_weights(
    const float* __restrict__ w1, const float* __restrict__ w2a,
    const float* __restrict__ w2b, const float* __restrict__ w3a,
    const float* __restrict__ w3s, ushort_t* __restrict__ ws) {
    __shared__ ushort_t tile[64][65];
    int b = blockIdx.x;
    const float* src; int Oo, Ot, R, C, t;
    if (b < 16)      { src = w2a; Oo = O_W2ab; Ot = O_W2aT; R = 256; C = 256; t = b; }
    else if (b < 32) { src = w2b; Oo = O_W2bb; Ot = O_W2bT; R = 256; C = 256; t = b - 16; }
    else if (b < 48) { src = w3a; Oo = O_W3ab; Ot = O_W3aT; R = 256; C = 256; t = b - 32; }
    else if (b < 52) { src = w1;  Oo = O_W1b;  Ot = O_W1T;  R = 256; C = 64;  t = b - 48; }
    else             { src = w3s; Oo = O_W3sb; Ot = O_W3sT; R = 256; C = 64;  t = b - 52; }
    int tr, tc;
    if (C == 256) { tr = t >> 2; tc = t & 3; } else { tr = t; tc = 0; }
    int r0 = tr * 64, c0 = tc * 64;

    union pack8 { ushort_t u[8]; uint4 q; };
    for (int it = threadIdx.x; it < 512; it += 256) {
        int r = it >> 3, c8 = (it & 7) << 3;
        const float* s = src + (r0 + r) * C + c0 + c8;
        pack8 p;
#pragma unroll
        for (int j = 0; j < 8; j++) { p.u[j] = f2bf(s[j]); tile[r][c8 + j] = p.u[j]; }
        *(uint4*)(ws + Oo + (r0 + r) * C + c0 + c8) = p.q;
    }
    __syncthreads();
    for (int it = threadIdx.x; it < 512; it += 256) {
        int cc = it >> 3, r8 = (it & 7) << 3;
        pack8 p;
#pragma unroll
        for (int j = 0; j < 8; j++) p.u[j] = tile[r8 + j][cc];
        *(uint4*)(ws + Ot + (c0 + cc) * R + r0 + r8) = p.q;
    }
}

// one 16x16 output tile of A[16,KLEN] @ B-slice (cols n0..n0+16), k window k0..k0+KLEN.
// A: bf16 LDS, row stride STRA, column-XOR-swizzled (c ^ ((r&7)<<3)).
// B: bf16 global, stored [n][k] row-major, row stride STRB.
template <int KLEN, int STRA, int STRB>
__device__ __forceinline__ f32x4 tile_gemm(const ushort_t* sA, const ushort_t* __restrict__ B,
                                           int lane, int n0, int k0, f32x4 acc) {
    const int row = lane & 15;
    const int kq = (lane >> 4) << 3;
    const int sw = (row & 7) << 3;
    const ushort_t* aptr = sA + row * STRA;
    const ushort_t* bptr = B + (n0 + row) * STRB + k0 + kq;
    if constexpr (KLEN >= 128) {
        f32x4 acc2 = {0.f, 0.f, 0.f, 0.f};
#pragma unroll
        for (int kb = 0; kb < KLEN; kb += 64) {
            bf16x8 a0 = *(const bf16x8*)(aptr + ((k0 + kb + kq) ^ sw));
            bf16x8 b0 = *(const bf16x8*)(bptr + kb);
            acc = __builtin_amdgcn_mfma_f32_16x16x32_bf16(a0, b0, acc, 0, 0, 0);
            bf16x8 a1 = *(const bf16x8*)(aptr + ((k0 + kb + 32 + kq) ^ sw));
            bf16x8 b1 = *(const bf16x8*)(bptr + kb + 32);
            acc2 = __builtin_amdgcn_mfma_f32_16x16x32_bf16(a1, b1, acc2, 0, 0, 0);
        }
        acc += acc2;
        return acc;
    } else {
#pragma unroll
        for (int kb = 0; kb < KLEN; kb += 32) {
            bf16x8 a = *(const bf16x8*)(aptr + ((k0 + kb + kq) ^ sw));
            bf16x8 b = *(const bf16x8*)(bptr + kb);
            acc = __builtin_amdgcn_mfma_f32_16x16x32_bf16(a, b, acc, 0, 0, 0);
        }
        return acc;
    }
}

__global__ __launch_bounds__(1024, 4) void net_main(
    const float* __restrict__ x, const float* __restrict__ xd,
    const float* __restrict__ b1, const float* __restrict__ b2a,
    const float* __restrict__ b2b, const float* __restrict__ b3a,
    const float* __restrict__ b3s, const float* __restrict__ wout,
    const float* __restrict__ scalar, const ushort_t* __restrict__ ws,
    float* __restrict__ out) {
    __shared__ __align__(16) ushort_t sX[RPB * 64];    // bf16 x, swizzled
    __shared__ __align__(16) float sXd[RPB * 64];      // f32 xdot, linear
    __shared__ __align__(16) ushort_t sZ[RPB * H];     // z -> later c2 = 2*p*z
    __shared__ __align__(16) ushort_t sY[RPB * H];     // y1 -> y2
    __shared__ __align__(16) ushort_t sZ12[RPB * H];   // z1_2 -> tz1
    __shared__ __align__(16) ushort_t sZ22[RPB * H];   // z2_2 -> tz2
    __shared__ __align__(16) ushort_t sZ13[RPB * H];   // u = wout*z1_3
    __shared__ __align__(16) ushort_t sZ23[RPB * H];   // z2_3 -> v = wout*z2_3
    __shared__ float sFJ1[RPB * 64];
    __shared__ float sFJ2[RPB * 64];
    __shared__ float sNB[RPB];

    const int tid = threadIdx.x;
    const int wid = tid >> 6;       // 0..15
    const int lane = tid & 63;
    const int row16 = lane & 15;    // MFMA D: this is the COLUMN index
    const int rq = lane >> 4;       // MFMA D: row = rq*4 + i
    const int R0 = blockIdx.x * RPB;

    // ---- Phase 0: stage x/xdot, write yy, zero accumulators
    float sc = scalar[0];
    {
        int r = tid >> 6, c = tid & 63;  // 1024 threads = exactly RPB*64
        float xv = x[(R0 + r) * 64 + c];
        sX[r * 64 + (c ^ ((r & 7) << 3))] = f2bf(xv);
        sXd[tid] = xd[(R0 + r) * 64 + c];
        out[YY_OFF + (R0 + r) * 64 + c] = sc;
        sFJ1[tid] = 0.f;
        sFJ2[tid] = 0.f;
        if (tid < RPB) sNB[tid] = 0.f;
    }
    __syncthreads();

    // ---- Phase 1: z = x@W1.T + b1, y1 = z*z   AND   z2_3 = x@W3s.T + b3s
    for (int t2 = wid; t2 < 32; t2 += 16) {
        f32x4 acc = {0.f, 0.f, 0.f, 0.f};
        if (t2 < 16) {
            int nt = t2;
            acc = tile_gemm<64, 64, 64>(sX, ws + O_W1b, lane, nt * 16, 0, acc);
            int c = nt * 16 + row16;
            float bias = b1[c];
#pragma unroll
            for (int i = 0; i < 4; i++) {
                int r = rq * 4 + i;
                int pos = r * H + (c ^ ((r & 7) << 3));
                float z = acc[i] + bias;
                sZ[pos] = f2bf(z);
                sY[pos] = f2bf(z * z);
            }
        } else {
            int nt = t2 - 16;
            acc = tile_gemm<64, 64, 64>(sX, ws + O_W3sb, lane, nt * 16, 0, acc);
            int c = nt * 16 + row16;
            float bias = b3s[c];
#pragma unroll
            for (int i = 0; i < 4; i++) {
                int r = rq * 4 + i;
                sZ23[r * H + (c ^ ((r & 7) << 3))] = f2bf(acc[i] + bias);
            }
        }
    }
    __syncthreads();

    // ---- Phase 2: z1_2 = y1@W2a.T + b2a ; z2_2 = y1@W2b.T + b2b
    for (int t2 = wid; t2 < 32; t2 += 16) {
        int nt = t2 & 15;
        const ushort_t* W = (t2 < 16) ? (ws + O_W2ab) : (ws + O_W2bb);
        const float* bb = (t2 < 16) ? b2a : b2b;
        ushort_t* dst = (t2 < 16) ? sZ12 : sZ22;
        f32x4 acc = {0.f, 0.f, 0.f, 0.f};
        acc = tile_gemm<H, H, H>(sY, W, lane, nt * 16, 0, acc);
        int c = nt * 16 + row16;
        float bias = bb[c];
#pragma unroll
        for (int i = 0; i < 4; i++) {
            int r = rq * 4 + i;
            dst[r * H + (c ^ ((r & 7) << 3))] = f2bf(acc[i] + bias);
        }
    }
    __syncthreads();

    // ---- Phase 3: y2 = z1_2 * z2_2 (same swizzle on all buffers -> raw index ok)
    for (int e = tid; e < RPB * H; e += 1024)
        sY[e] = f2bf(bf2f(sZ12[e]) * bf2f(sZ22[e]));
    __syncthreads();

    // ---- Phase 4: z1_3 = y2@W3a.T + b3a ; y3 out; u,v; nb reduction
    {
        int nt = wid;
        f32x4 acc = {0.f, 0.f, 0.f, 0.f};
        acc = tile_gemm<H, H, H>(sY, ws + O_W3ab, lane, nt * 16, 0, acc);
        int c = nt * 16 + row16;
        float bias = b3a[c];
        float wo = wout[c];
#pragma unroll
        for (int i = 0; i < 4; i++) {
            int r = rq * 4 + i;
            int pos = r * H + (c ^ ((r & 7) << 3));
            float z13 = acc[i] + bias;
            float z23 = bf2f(sZ23[pos]);
            float y3 = z13 * z23;
            out[Y_OFF + (R0 + r) * H + c] = y3;
            sZ13[pos] = f2bf(wo * z13);
            sZ23[pos] = f2bf(wo * z23);
            float val = wo * y3;  // contribution to numerical_b (sum over c)
            val += __shfl_xor(val, 1);
            val += __shfl_xor(val, 2);
            val += __shfl_xor(val, 4);
            val += __shfl_xor(val, 8);
            if (row16 == 0) atomicAdd(&sNB[r], val);
        }
    }
    __syncthreads();

    // ---- Phase 5: t = v@W3a (via W3aT); fold: tz1 = t*z1_2, tz2 = t*z2_2
    {
        int nt = wid;
        f32x4 acc = {0.f, 0.f, 0.f, 0.f};
        acc = tile_gemm<H, H, H>(sZ23, ws + O_W3aT, lane, nt * 16, 0, acc);
        int c = nt * 16 + row16;
#pragma unroll
        for (int i = 0; i < 4; i++) {
            int r = rq * 4 + i;
            int pos = r * H + (c ^ ((r & 7) << 3));
            float t = acc[i];
            float z12o = bf2f(sZ12[pos]);
            float z22o = bf2f(sZ22[pos]);
            sZ12[pos] = f2bf(t * z12o);
            sZ22[pos] = f2bf(t * z22o);
        }
    }
    __syncthreads();

    // ---- Phase 6: p = tz1@W2b + tz2@W2a (transposed copies); c2 = 2*p*z
    {
        int nt = wid;
        f32x4 acc = {0.f, 0.f, 0.f, 0.f};
        acc = tile_gemm<H, H, H>(sZ12, ws + O_W2bT, lane, nt * 16, 0, acc);
        acc = tile_gemm<H, H, H>(sZ22, ws + O_W2aT, lane, nt * 16, 0, acc);
        int c = nt * 16 + row16;
#pragma unroll
        for (int i = 0; i < 4; i++) {
            int r = rq * 4 + i;
            int pos = r * H + (c ^ ((r & 7) << 3));
            sZ[pos] = f2bf(2.f * acc[i] * bf2f(sZ[pos]));
        }
    }
    __syncthreads();

    // ---- Phase 7: fj1 = u@W3s (W3sT), fj2 = c2@W1 (W1T), K-split x4 across waves
    {
        int task = wid;                 // 0..15: fj1 partials; 16..31: fj2 partials
        for (int t2 = task; t2 < 32; t2 += 16) {
            int ntile = t2 & 3;         // 4 n-tiles of 16 (N=64)
            int kch = (t2 >> 2) & 3;    // 4 K-chunks of 64
            f32x4 acc = {0.f, 0.f, 0.f, 0.f};
            const ushort_t* A = (t2 < 16) ? sZ13 : sZ;
            const ushort_t* B = (t2 < 16) ? (ws + O_W3sT) : (ws + O_W1T);
            float* dst = (t2 < 16) ? sFJ1 : sFJ2;
            acc = tile_gemm<64, H, H>(A, B, lane, ntile * 16, kch * 64, acc);
            int c = ntile * 16 + row16;
#pragma unroll
            for (int i = 0; i < 4; i++)
                atomicAdd(&dst[(rq * 4 + i) * 64 + c], acc[i]);
        }
    }
    __syncthreads();

    // ---- Phase 8: bdot[r] = sum_i (fj1+fj2)[r,i]*xdot[r,i]; write nb
    {
        int r = tid >> 6, j = tid & 63;
        float s = (sFJ1[r * 64 + j] + sFJ2[r * 64 + j]) * sXd[r * 64 + j];
        s += __shfl_xor(s, 1);
        s += __shfl_xor(s, 2);
        s += __shfl_xor(s, 4);
        s += __shfl_xor(s, 8);
        s += __shfl_xor(s, 16);
        s += __shfl_xor(s, 32);
        if (j == 0) out[BDOT_OFF + R0 + r] = s;
        if (tid < RPB) out[NB_OFF + R0 + tid] = sNB[tid];
    }
}

extern "C" void kernel_launch(void* const* d_in, const int* in_sizes, int n_in,
                              void* d_out, int out_size, void* d_ws, size_t ws_size,
                              hipStream_t stream) {
    (void)in_sizes; (void)n_in; (void)out_size; (void)ws_size;
    const float* x = (const float*)d_in[0];
    const float* xd = (const float*)d_in[1];
    const float* w1 = (const float*)d_in[2];
    const float* b1 = (const float*)d_in[3];
    const float* w2a = (const float*)d_in[4];
    const float* b2a = (const float*)d_in[5];
    const float* w2b = (const float*)d_in[6];
    const float* b2b = (const float*)d_in[7];
    const float* w3a = (const float*)d_in[8];
    const float* b3a = (const float*)d_in[9];
    const float* w3s = (const float*)d_in[10];
    const float* b3s = (const float*)d_in[11];
    const float* wout = (const float*)d_in[12];
    const float* scalar = (const float*)d_in[13];
    ushort_t* ws = (ushort_t*)d_ws;
    float* out = (float*)d_out;

    prep_weights<<<56, 256, 0, stream>>>(w1, w2a, w2b, w3a, w3s, ws);
    net_main<<<256, 1024, 0, stream>>>(x, xd, b1, b2a, b2b, b3a, b3s, wout, scalar, ws, out);
}